// Round 4
// baseline (152.414 us; speedup 1.0000x reference)
//
#include <hip/hip_runtime.h>
#include <math.h>

#define Bsz 16
#define Gg  20000
#define Dd  256
#define Kk  2048
#define NB  8192          // 13-bit key bins: key = bits>>17
#define CCAP 2048
#define TBL_N 1024
#define NSL  8            // slices per row
#define SLE  2560         // elements per slice (last slice ragged: 2080)
#define SLF4 640          // float4 per slice

typedef float f32x4 __attribute__((ext_vector_type(4)));

// Static device scratch (harness poisons d_ws unconditionally; we avoid it).
// Every consumed element is rewritten each launch:
//  g_F: all 1025 rows (k1); g_hist: all 16x8x8192 (k1, full overwrite, no zeroing race);
//  g_cnt: zeroed in k1; g_cand/g_candi: first n entries (k2), only first n read;
//  g_sgt/g_needbin: k2; g_cidx/g_esel: k3 kept [0,n_b) + pad [n_b,Kk).
__device__ float    g_F[(TBL_N + 1) * Dd];
__device__ int      g_cidx[Bsz * Kk];
__device__ float    g_esel[Bsz * Kk];
__device__ unsigned g_hist[Bsz][NSL][NB];        // 4 MB
__device__ unsigned g_cand[Bsz][CCAP];
__device__ int      g_candi[Bsz][CCAP];
__device__ unsigned g_cnt[Bsz];
__device__ unsigned g_sgt[Bsz][NSL];
__device__ unsigned g_needbin[Bsz];

__device__ __forceinline__ float gelu_exact(float x) {
  return 0.5f * x * (1.0f + erff(x * 0.70710678118654752f));
}

// exclusive scan over 1024 threads (16 waves); leading barrier protects s_ws reuse
__device__ __forceinline__ unsigned scan1024_excl(unsigned v, unsigned* s_ws,
                                                  unsigned* tot) {
  const int lane = threadIdx.x & 63, wid = threadIdx.x >> 6;
  __syncthreads();
  unsigned incl = v;
  #pragma unroll
  for (int off = 1; off < 64; off <<= 1) {
    unsigned u = (unsigned)__shfl_up((int)incl, off);
    if (lane >= off) incl += u;
  }
  if (lane == 63) s_ws[wid] = incl;
  __syncthreads();
  if (wid == 0) {
    unsigned w = (lane < 16) ? s_ws[lane] : 0u;
    unsigned wi = w;
    #pragma unroll
    for (int off = 1; off < 16; off <<= 1) {
      unsigned u = (unsigned)__shfl_up((int)wi, off);
      if (lane >= off) wi += u;
    }
    if (lane < 16) s_ws[lane] = wi - w;
    if (lane == 15) s_ws[16] = wi;
  }
  __syncthreads();
  if (tot) *tot = s_ws[16];
  return s_ws[wid] + incl - v;
}

// ===== k1: blocks 0..127 per-slice histograms ∥ blocks 128..255 F-table (8 nodes each) =====
__global__ __launch_bounds__(1024) void k_hist_table(
    const float* __restrict__ expr,
    const float* __restrict__ w1, const float* __restrict__ b1,
    const float* __restrict__ w2, const float* __restrict__ b2)
{
  union SM {
    unsigned hist[NB];                              // 32 KB
    struct { float h[9][256]; float t[32][257]; } tab; // 42.1 KB
  };
  __shared__ SM u;
  const int tid = threadIdx.x;

  if (blockIdx.x < 128) {
    // ---- histogram role: one slice of one row ----
    const int row = blockIdx.x >> 3, slice = blockIdx.x & 7;
    for (int i = tid; i < NB; i += 1024) u.hist[i] = 0u;
    if (slice == 0 && tid == 0) g_cnt[row] = 0u;
    __syncthreads();
    if (tid < SLF4) {
      const int g0 = slice * SLE + tid * 4;
      if (g0 < Gg) {
        float4 v = ((const float4*)(expr + (size_t)row * Gg))[slice * SLF4 + tid];
        #pragma unroll
        for (int j = 0; j < 4; ++j) {
          unsigned k = __float_as_uint(((const float*)&v)[j]) >> 17;
          if (k > NB - 1) k = NB - 1;
          atomicAdd(&u.hist[k], 1u);
        }
      }
    }
    __syncthreads();
    for (int i = tid; i < NB; i += 1024) g_hist[row][slice][i] = u.hist[i];
    return;
  }

  // ---- table role: 8 nodes per block; block 128 also computes node 1024 ----
  const int j0 = (blockIdx.x - 128) * 8;
  const bool extra = (blockIdx.x == 128);
  const int e  = tid & 255;
  const int jj = tid >> 8;                 // 0..3, wave-uniform
  {
    float x0 = (float)(j0 + jj)     * (1.0f / TBL_N);
    float x1 = (float)(j0 + 4 + jj) * (1.0f / TBL_N);
    u.tab.h[jj][e]     = gelu_exact(x0 * w1[e] + b1[e]);
    u.tab.h[jj + 4][e] = gelu_exact(x1 * w1[e] + b1[e]);
    if (extra && jj == 0) u.tab.h[8][e] = gelu_exact(1.0f * w1[e] + b1[e]);
  }
  float acc0 = b2[e], acc1 = b2[e], acc2 = b2[e];
  const int er = tid >> 3, q = tid & 7;    // stage: 128 rows x 8 d-quads
  #pragma unroll 1
  for (int c = 0; c < 8; ++c) {
    __syncthreads();                        // h ready (c==0) / prev compute done
    #pragma unroll
    for (int half = 0; half < 2; ++half) {
      int r = er + half * 128;
      float4 wv = *(const float4*)(w2 + (size_t)r * 256 + c * 32 + q * 4);
      u.tab.t[q * 4 + 0][r] = wv.x;
      u.tab.t[q * 4 + 1][r] = wv.y;
      u.tab.t[q * 4 + 2][r] = wv.z;
      u.tab.t[q * 4 + 3][r] = wv.w;
    }
    __syncthreads();
    #pragma unroll
    for (int dd = 0; dd < 32; ++dd) {
      float tv = u.tab.t[dd][e];
      acc0 += u.tab.h[jj][c * 32 + dd]     * tv;
      acc1 += u.tab.h[jj + 4][c * 32 + dd] * tv;
      if (extra) acc2 += u.tab.h[8][c * 32 + dd] * tv;
    }
  }
  g_F[(size_t)(j0 + jj) * Dd + e]     = acc0;
  g_F[(size_t)(j0 + 4 + jj) * Dd + e] = acc1;
  if (extra && jj == 0) g_F[(size_t)TBL_N * Dd + e] = acc2;
}

// ===== k2: per-slice threshold-bin scan + candidate collect + key>B counts (128 blocks) =====
__global__ __launch_bounds__(1024) void k_thresh(const float* __restrict__ expr)
{
  __shared__ unsigned s_ws[17];
  __shared__ unsigned s_B, s_needbin, s_remK;
  __shared__ int s_done;
  const int tid = threadIdx.x;
  const int row = blockIdx.x >> 3, slice = blockIdx.x & 7;

  if (tid == 0) { s_remK = Kk; s_done = 0; }
  __syncthreads();

  // find 13-bit bin of the K-th largest (descending chunks of 1024 bins)
  for (int c = 0; c < NB / 1024 && !s_done; ++c) {
    const int idx = NB - 1 - c * 1024 - tid;
    unsigned partial = 0;
    #pragma unroll
    for (int s2 = 0; s2 < NSL; ++s2) partial += g_hist[row][s2][idx];
    unsigned tot;
    unsigned excl = scan1024_excl(partial, s_ws, &tot);
    const unsigned remK = s_remK;
    if (excl < remK && remK <= excl + partial) {
      s_B = (unsigned)idx; s_needbin = remK - excl; s_done = 1;
    }
    __syncthreads();
    if (!s_done && tid == 0) s_remK = remK - tot;
    __syncthreads();
  }
  const unsigned B = s_B, needbin = s_needbin;
  if (slice == 0 && tid == 0) g_needbin[row] = needbin;

  // slice pass: collect candidates (key==B) + count key>B
  unsigned keyGt = 0;
  if (tid < SLF4) {
    const int g0 = slice * SLE + tid * 4;
    if (g0 < Gg) {
      float4 v = ((const float4*)(expr + (size_t)row * Gg))[slice * SLF4 + tid];
      #pragma unroll
      for (int j = 0; j < 4; ++j) {
        unsigned bits = __float_as_uint(((const float*)&v)[j]);
        unsigned k = bits >> 17;
        if (k > NB - 1) k = NB - 1;
        if (k > B) keyGt++;
        else if (k == B) {
          unsigned p = atomicAdd(&g_cnt[row], 1u);
          if (p < CCAP) { g_cand[row][p] = bits; g_candi[row][p] = g0 + j; }
        }
      }
    }
  }
  unsigned tot;
  scan1024_excl(keyGt, s_ws, &tot);
  if (tid == 0) g_sgt[row][slice] = tot;
}

// ===== k3: exact threshold (redundant/block) + per-slice compaction + pad/cls/mask =====
__global__ __launch_bounds__(1024) void k_compact(
    const float* __restrict__ expr, const float* __restrict__ cls,
    float* __restrict__ out)
{
  __shared__ unsigned s_ws[17];
  __shared__ unsigned s_cand[CCAP];    // 8 KB
  __shared__ int      s_ci[CCAP];      // 8 KB
  __shared__ unsigned s_T, s_ne, s_rankT, s_cGt, s_cEq;
  const int tid = threadIdx.x;
  const int row = blockIdx.x >> 3, slice = blockIdx.x & 7;

  const unsigned needbin = g_needbin[row];
  unsigned n = g_cnt[row]; if (n > CCAP) n = CCAP;
  for (unsigned i = tid; i < n; i += 1024) { s_cand[i] = g_cand[row][i]; s_ci[i] = g_candi[row][i]; }
  if (tid == 0) { s_cGt = 0u; s_cEq = 0u; }
  __syncthreads();

  // exact 32-bit threshold among candidates (tie-aware)
  for (unsigned i = tid; i < n; i += 1024) {
    unsigned v = s_cand[i];
    unsigned rank = 0, eq = 0;
    for (unsigned j = 0; j < n; ++j) {
      unsigned uu = s_cand[j];
      rank += (uu > v) ? 1u : 0u;
      eq   += (uu == v) ? 1u : 0u;
    }
    if (rank < needbin && needbin <= rank + eq) {
      s_T = v; s_ne = needbin - rank; s_rankT = rank;   // unique value class
    }
  }
  __syncthreads();
  const unsigned T = s_T;
  const unsigned need_eq = (T == 0u) ? 0u : s_ne;
  const unsigned n_b = (Kk - needbin) + s_rankT + need_eq;

  // slice bases: gt = key>B prefix + cand(bits>T) prefix; eq = cand(bits==T) prefix
  const int start = slice * SLE;
  unsigned pg = 0, pe = 0;
  for (unsigned i = tid; i < n; i += 1024) {
    if (s_ci[i] < start) {
      unsigned cb = s_cand[i];
      pg += (cb > T) ? 1u : 0u;
      pe += (cb == T) ? 1u : 0u;
    }
  }
  atomicAdd(&s_cGt, pg); atomicAdd(&s_cEq, pe);
  __syncthreads();
  unsigned kg = 0;
  for (int s2 = 0; s2 < slice; ++s2) kg += g_sgt[row][s2];
  const unsigned base_gt = kg + s_cGt;
  const unsigned base_eq = s_cEq;

  // compact this slice (one block-wide scan)
  const int g0 = start + tid * 4;
  const bool act = (tid < SLF4) && (g0 < Gg);
  float4 v = {0.f, 0.f, 0.f, 0.f};
  unsigned gt = 0, eq = 0;
  if (act) {
    v = ((const float4*)(expr + (size_t)row * Gg))[g0 >> 2];
    #pragma unroll
    for (int j = 0; j < 4; ++j) {
      unsigned bits = __float_as_uint(((const float*)&v)[j]);
      gt += (bits > T) ? 1u : 0u;
      eq += (bits == T) ? 1u : 0u;
    }
  }
  unsigned tot;
  unsigned excl = scan1024_excl((gt << 16) | eq, s_ws, &tot);
  if (act) {
    unsigned thr_gt = base_gt + (excl >> 16);
    unsigned thr_eq = base_eq + (excl & 0xFFFFu);
    unsigned lgt = 0, leq = 0;
    #pragma unroll
    for (int j = 0; j < 4; ++j) {
      float vj = ((const float*)&v)[j];
      unsigned bits = __float_as_uint(vj);
      unsigned cur_gt = thr_gt + lgt, cur_eq = thr_eq + leq;
      bool isgt = bits > T, iseq = bits == T;
      bool kept = isgt || (iseq && cur_eq < need_eq);
      if (kept) {
        unsigned pos = cur_gt + ((cur_eq < need_eq) ? cur_eq : need_eq);
        g_cidx[row * Kk + pos] = g0 + j;
        g_esel[row * Kk + pos] = vj;
      }
      lgt += isgt ? 1u : 0u;
      leq += iseq ? 1u : 0u;
    }
  }

  // padding (slice owns k in [slice*256, slice*256+256))
  if (tid < 256) {
    int k = slice * 256 + tid;
    if ((unsigned)k >= n_b) { g_cidx[row * Kk + k] = -1; g_esel[row * Kk + k] = 0.0f; }
  }
  // cls token
  if (slice == 0 && tid < Dd) out[(size_t)row * (Kk + 1) * Dd + tid] = cls[tid];
  // mask
  float* maskp = out + (size_t)Bsz * (Kk + 1) * Dd + (size_t)row * (Kk + 1);
  if (tid < 256) {
    int mi = slice * 256 + tid;
    maskp[mi] = (mi == 0) ? 1.0f : (((unsigned)(mi - 1) < n_b) ? 1.0f : 0.0f);
  }
  if (slice == 7 && tid == 256) maskp[Kk] = (((unsigned)(Kk - 1) < n_b) ? 1.0f : 0.0f);
}

// ===== k4: gather tokens via table lerp — 2 slots/wave, branch-free =====
__global__ __launch_bounds__(256) void k_gather(
    const float* __restrict__ gene_emb, float* __restrict__ out)
{
  const int tid  = threadIdx.x;
  const int lane = tid & 63;
  const int s0   = (blockIdx.x * 4 + (tid >> 6)) * 2;   // even: pair stays in one row
  const int e0   = lane * 4;

  const int g0 = g_cidx[s0];
  const int g1 = g_cidx[s0 + 1];
  const int bb = s0 >> 11, k0 = s0 & 2047;
  float* op = out + (size_t)bb * ((Kk + 1) * Dd) + (size_t)(k0 + 1) * Dd + e0;

  const float m0 = (g0 >= 0) ? 1.0f : 0.0f;
  const float m1 = (g1 >= 0) ? 1.0f : 0.0f;
  const int  gg0 = (g0 >= 0) ? g0 : 0;
  const int  gg1 = (g1 >= 0) ? g1 : 0;

  float xs0 = g_esel[s0]     * (float)TBL_N;
  float xs1 = g_esel[s0 + 1] * (float)TBL_N;
  int j0 = (int)xs0; j0 = (j0 < 0) ? 0 : ((j0 > TBL_N - 1) ? TBL_N - 1 : j0);
  int j1 = (int)xs1; j1 = (j1 < 0) ? 0 : ((j1 > TBL_N - 1) ? TBL_N - 1 : j1);
  float t0 = xs0 - (float)j0;
  float t1 = xs1 - (float)j1;

  const float* fa0 = g_F + (size_t)j0 * Dd + e0;
  const float* fa1 = g_F + (size_t)j1 * Dd + e0;
  float4 a0  = *(const float4*)fa0;
  float4 b0  = *(const float4*)(fa0 + Dd);
  float4 ge0 = *(const float4*)(gene_emb + (size_t)gg0 * Dd + e0);
  float4 a1  = *(const float4*)fa1;
  float4 b1  = *(const float4*)(fa1 + Dd);
  float4 ge1 = *(const float4*)(gene_emb + (size_t)gg1 * Dd + e0);

  f32x4 o0, o1;
  o0.x = m0 * (ge0.x + a0.x + (b0.x - a0.x) * t0);
  o0.y = m0 * (ge0.y + a0.y + (b0.y - a0.y) * t0);
  o0.z = m0 * (ge0.z + a0.z + (b0.z - a0.z) * t0);
  o0.w = m0 * (ge0.w + a0.w + (b0.w - a0.w) * t0);
  o1.x = m1 * (ge1.x + a1.x + (b1.x - a1.x) * t1);
  o1.y = m1 * (ge1.y + a1.y + (b1.y - a1.y) * t1);
  o1.z = m1 * (ge1.z + a1.z + (b1.z - a1.z) * t1);
  o1.w = m1 * (ge1.w + a1.w + (b1.w - a1.w) * t1);

  __builtin_nontemporal_store(o0, (f32x4*)op);
  __builtin_nontemporal_store(o1, (f32x4*)(op + Dd));
}

extern "C" void kernel_launch(void* const* d_in, const int* in_sizes, int n_in,
                              void* d_out, int out_size, void* d_ws, size_t ws_size,
                              hipStream_t stream)
{
  const float* expr     = (const float*)d_in[0];
  const float* gene_emb = (const float*)d_in[1];
  const float* w1       = (const float*)d_in[2];
  const float* b1       = (const float*)d_in[3];
  const float* w2       = (const float*)d_in[4];
  const float* b2       = (const float*)d_in[5];
  const float* cls      = (const float*)d_in[6];
  float* out = (float*)d_out;
  (void)d_ws; (void)ws_size;

  hipLaunchKernelGGL(k_hist_table, dim3(256),             dim3(1024), 0, stream,
                     expr, w1, b1, w2, b2);
  hipLaunchKernelGGL(k_thresh,     dim3(128),             dim3(1024), 0, stream, expr);
  hipLaunchKernelGGL(k_compact,    dim3(128),             dim3(1024), 0, stream,
                     expr, cls, out);
  hipLaunchKernelGGL(k_gather,     dim3((Bsz * Kk) / 8),  dim3(256),  0, stream,
                     gene_emb, out);
}